// Round 3
// baseline (298.364 us; speedup 1.0000x reference)
//
#include <hip/hip_runtime.h>
#include <stdint.h>

#define B_ 4
#define C_ 256
#define H_ 64
#define W_ 64
#define O_ 256
#define K_ 9
#define CK 2304     // K_*C_  (ck = k*256 + c, k-major)
#define HW 4096
#define NTOT 16384  // B_*HW

typedef __bf16 bf16x8 __attribute__((ext_vector_type(8)));
typedef float f32x4 __attribute__((ext_vector_type(4)));
typedef float f32x2 __attribute__((ext_vector_type(2)));
typedef f32x2 __attribute__((aligned(4))) f32x2u;  // 4B-aligned vector load

__device__ __forceinline__ uint16_t f2bf(float f) {
  uint32_t u = __builtin_bit_cast(uint32_t, f);
  return (uint16_t)((u + 0x7FFFu + ((u >> 16) & 1u)) >> 16);
}

__device__ __forceinline__ uint32_t pk_bf16(float a, float b) {
  uint16_t lo = __builtin_bit_cast(uint16_t, (__bf16)a);
  uint16_t hi = __builtin_bit_cast(uint16_t, (__bf16)b);
  return (uint32_t)lo | ((uint32_t)hi << 16);
}

// ---------------- K0: weight fp32 [O][C][3][3] -> bf16 wb[O][k*256+c] ----------------
__global__ void k0_wconv(const float* __restrict__ weight, uint16_t* __restrict__ wb) {
  int idx = blockIdx.x * 256 + threadIdx.x;
  if (idx >= O_ * CK) return;
  int o = idx / CK;
  int rem = idx - o * CK;
  int k = rem >> 8;
  int c = rem & 255;
  wb[idx] = f2bf(weight[(o * C_ + c) * K_ + k]);
}

// ---------------- K1: offset conv (fp32) -> py/px/mask [b][k][h][w] ----------------
__global__ void k1_offconv(const float* __restrict__ x, const float* __restrict__ w_om,
                           const float* __restrict__ b_om, float* __restrict__ pypxmk) {
  int bx = blockIdx.x;
  int jq = bx % 7;
  int h = (bx / 7) % H_;
  int b = bx / (7 * H_);
  int t = threadIdx.x;
  int w = t & 63;
  int cs = __builtin_amdgcn_readfirstlane(t >> 6);

  float acc[4] = {0.f, 0.f, 0.f, 0.f};
  const float* xb = x + (b * C_) * HW;

  for (int ci = 0; ci < 64; ++ci) {
    int c = cs * 64 + ci;
    const float* xr = xb + c * HW;
    float xv[3][3];
#pragma unroll
    for (int r = 0; r < 3; ++r) {
      int y = h - 1 + r;
      bool yv = ((unsigned)y < 64u);
#pragma unroll
      for (int dx = 0; dx < 3; ++dx) {
        int xx = w - 1 + dx;
        bool v = yv && ((unsigned)xx < 64u);
        xv[r][dx] = v ? xr[y * 64 + xx] : 0.f;
      }
    }
    const float* wp = w_om + ((jq * 4) * C_ + c) * 9;
#pragma unroll
    for (int jj = 0; jj < 4; ++jj) {
      int j = jq * 4 + jj;
      int jeff = (j < 27) ? jj : 0;  // jq=6,jj=3 is dead; avoid OOB read
      const float* wj = wp + jeff * (C_ * 9);
      float a = 0.f;
#pragma unroll
      for (int r = 0; r < 3; ++r)
#pragma unroll
        for (int dx = 0; dx < 3; ++dx)
          a = fmaf(xv[r][dx], wj[r * 3 + dx], a);
      acc[jj] += a;
    }
  }

  __shared__ float red[4][4][64];
#pragma unroll
  for (int jj = 0; jj < 4; ++jj) red[cs][jj][w] = acc[jj];
  __syncthreads();

  int jj = t >> 6;
  int j = jq * 4 + jj;
  if (j < 27) {
    float s = red[0][jj][w] + red[1][jj][w] + red[2][jj][w] + red[3][jj][w] + b_om[j];
    float* pyA = pypxmk;
    float* pxA = pypxmk + 147456;
    float* mkA = pypxmk + 294912;
    if (j < 18) {
      int k = j >> 1;
      int off = (b * 9 + k) * HW + h * 64 + w;
      if ((j & 1) == 0)
        pyA[off] = (float)(h - 1 + k / 3) + s;   // absolute sample y
      else
        pxA[off] = (float)(w - 1 + k % 3) + s;   // absolute sample x
    } else {
      int k = j - 18;
      mkA[(b * 9 + k) * HW + h * 64 + w] = 1.f / (1.f + __expf(-s));
    }
  }
}

// ---------------- K2: bilinear gather -> cols bf16 [b*hw][k*256+c] ----------------
// Grid = (b, h, cg): 2048 blocks; all 9 k's, one 32-channel group per block.
// Per-k setup folds corner validity, mask, AND the x-clamp select into 4 row
// weights (wa0,wb0,wa1,wb1), so the inner loop is: 2 float2 loads + 4 FMA per
// (k,c) sample — no cndmask, no per-sample address clamping.
__global__ void __launch_bounds__(256, 4)
k2_cols(const float* __restrict__ x, const float* __restrict__ pypxmk,
        uint16_t* __restrict__ cols) {
  int bx = blockIdx.x;
  int cg = bx & 7;
  int h = (bx >> 3) & 63;
  int b = bx >> 9;
  int t = threadIdx.x;
  int w = t & 63;
  int g = t >> 6;

  const float* pyA = pypxmk;
  const float* pxA = pypxmk + 147456;
  const float* mkA = pypxmk + 294912;

  __shared__ uint16_t tile[64 * 290];  // 37,120 B -> 4 blocks/CU (16 waves)
  const float* xb = x + b * C_ * HW;
  int cbase = cg * 32 + g * 8;

  // ---- per-k sampling state: 4 weights + 2 row offsets ----
  float wa0[9], wb0[9], wa1[9], wb1[9];
  int a0[9], a1[9];
#pragma unroll
  for (int k = 0; k < 9; ++k) {
    int poff = (b * 9 + k) * HW + h * 64 + w;
    float py = pyA[poff];
    float px = pxA[poff];
    float mk = mkA[poff];
    float fy0 = floorf(py), fx0 = floorf(px);
    float ly = py - fy0, lx = px - fx0;
    int y0 = (int)fy0, x0 = (int)fx0;
    bool vy0 = ((unsigned)y0 < 64u), vy1 = ((unsigned)(y0 + 1) < 64u);
    bool vx0 = ((unsigned)x0 < 64u), vx1 = ((unsigned)(x0 + 1) < 64u);
    float w00 = (vy0 && vx0) ? (1.f - ly) * (1.f - lx) * mk : 0.f;
    float w01 = (vy0 && vx1) ? (1.f - ly) * lx * mk : 0.f;
    float w10 = (vy1 && vx0) ? ly * (1.f - lx) * mk : 0.f;
    float w11 = (vy1 && vx1) ? ly * lx * mk : 0.f;
    // pair is loaded at bx0=clamp(x0,0,62): element .x sits at cx0 unless
    // x0>=63 (sel0), element .y sits at cx1 unless x0<0 (!sel1).
    bool sel0 = (x0 >= 63);
    bool sel1 = (x0 >= 0);
    wa0[k] = (sel0 ? 0.f : w00) + (sel1 ? 0.f : w01);
    wb0[k] = (sel0 ? w00 : 0.f) + (sel1 ? w01 : 0.f);
    wa1[k] = (sel0 ? 0.f : w10) + (sel1 ? 0.f : w11);
    wb1[k] = (sel0 ? w10 : 0.f) + (sel1 ? w11 : 0.f);
    int bx0 = min(max(x0, 0), 62);
    a0[k] = min(max(y0, 0), 63) * 64 + bx0;
    a1[k] = min(max(y0 + 1, 0), 63) * 64 + bx0;
  }

  // ---- gather: 4 c-pairs x 9 k, loads batched in two k-groups for MLP ----
#pragma unroll
  for (int cp = 0; cp < 4; ++cp) {
    const float* xcA = xb + (cbase + cp * 2) * HW;
    const float* xcB = xcA + HW;
    uint16_t* trow = &tile[w * 290 + cp * 2 + g * 8];
#pragma unroll
    for (int kb = 0; kb < 2; ++kb) {  // k 0..4, then 5..8
      int k0 = kb * 5;
      int kn = kb ? 4 : 5;
      f32x2 pA0[5], pA1[5], pB0[5], pB1[5];
#pragma unroll
      for (int kk = 0; kk < 5; ++kk) {
        if (kk < kn) {
          int k = k0 + kk;
          pA0[kk] = *(const f32x2u*)&xcA[a0[k]];
          pA1[kk] = *(const f32x2u*)&xcA[a1[k]];
          pB0[kk] = *(const f32x2u*)&xcB[a0[k]];
          pB1[kk] = *(const f32x2u*)&xcB[a1[k]];
        }
      }
#pragma unroll
      for (int kk = 0; kk < 5; ++kk) {
        if (kk < kn) {
          int k = k0 + kk;
          float rA = wa0[k] * pA0[kk].x + wb0[k] * pA0[kk].y +
                     wa1[k] * pA1[kk].x + wb1[k] * pA1[kk].y;
          float rB = wa0[k] * pB0[kk].x + wb0[k] * pB0[kk].y +
                     wa1[k] * pB1[kk].x + wb1[k] * pB1[kk].y;
          *(uint32_t*)&trow[k * 32] = pk_bf16(rA, rB);
        }
      }
    }
  }
  __syncthreads();

  // flush: 64 rows x 144 dwords; conflict-free LDS reads, 64B-coalesced stores
#pragma unroll
  for (int it = 0; it < 36; ++it) {
    int u = t + it * 256;
    int wu = u / 144;
    int rem = u - wu * 144;        // dword col: rem = k*16 + cd, cd in 0..15
    int k = rem >> 4;
    int cd = rem & 15;
    uint32_t val = *(const uint32_t*)&tile[wu * 290 + rem * 2];
    int n = b * HW + h * 64 + wu;
    int dst = n * CK + k * 256 + cg * 32 + cd * 2;
    *(uint32_t*)&cols[dst] = val;
  }
}

// ---------------- K3: GEMM dst[b][o][hw] (+)= wb[o][ck] . cols[n][ck] ----------------
// M=256, N=16384. 128x128 tile, BK=32, 4 waves (2x2), 16x16x32 bf16 MFMA.
// Split-K capable: grid = 256 * nsplit; block bx>>8 selects K-range and partial dst.
__global__ void k3_gemm(const uint16_t* __restrict__ wb, const uint16_t* __restrict__ cols,
                        const float* __restrict__ bias, float* __restrict__ dst,
                        int ktn, int withBias) {
  int bx = blockIdx.x;
  int ks = bx >> 8;
  int bxx = bx & 255;
  int mt = bxx & 1;
  int nt = bxx >> 1;
  int o0 = mt * 128;
  int n0 = nt * 128;
  int t = threadIdx.x;
  int lane = t & 63;
  int wid = t >> 6;
  int wm = wid >> 1, wn = wid & 1;
  int lr = lane & 15, q = lane >> 4;

  __shared__ __align__(16) uint16_t As[128 * 32];
  __shared__ __align__(16) uint16_t Bs[128 * 32];

  f32x4 acc[4][4];
  const f32x4 zero = {0.f, 0.f, 0.f, 0.f};
#pragma unroll
  for (int i = 0; i < 4; ++i)
#pragma unroll
    for (int j = 0; j < 4; ++j) acc[i][j] = zero;

  int r0 = t >> 2;          // 0..63: tile row this thread stages
  int koff = (t & 3) * 8;   // 8 bf16 = 16B per lane
  int kb = ks * ktn * 32;
  const uint16_t* gA = wb + (o0 + r0) * CK + kb + koff;
  const uint16_t* gB = cols + (n0 + r0) * CK + kb + koff;

  for (int kt = 0; kt < ktn; ++kt) {
    int k0 = kt * 32;
    __builtin_amdgcn_global_load_lds(
        (const __attribute__((address_space(1))) uint32_t*)(gA + k0),
        (__attribute__((address_space(3))) uint32_t*)&As[t * 8], 16, 0, 0);
    __builtin_amdgcn_global_load_lds(
        (const __attribute__((address_space(1))) uint32_t*)(gA + 64 * CK + k0),
        (__attribute__((address_space(3))) uint32_t*)&As[2048 + t * 8], 16, 0, 0);
    __builtin_amdgcn_global_load_lds(
        (const __attribute__((address_space(1))) uint32_t*)(gB + k0),
        (__attribute__((address_space(3))) uint32_t*)&Bs[t * 8], 16, 0, 0);
    __builtin_amdgcn_global_load_lds(
        (const __attribute__((address_space(1))) uint32_t*)(gB + 64 * CK + k0),
        (__attribute__((address_space(3))) uint32_t*)&Bs[2048 + t * 8], 16, 0, 0);
    __syncthreads();

    bf16x8 aF[4], bF[4];
#pragma unroll
    for (int i = 0; i < 4; ++i)
      aF[i] = *(const bf16x8*)&As[(wm * 64 + i * 16 + lr) * 32 + q * 8];
#pragma unroll
    for (int j = 0; j < 4; ++j)
      bF[j] = *(const bf16x8*)&Bs[(wn * 64 + j * 16 + lr) * 32 + q * 8];
#pragma unroll
    for (int i = 0; i < 4; ++i)
#pragma unroll
      for (int j = 0; j < 4; ++j)
        acc[i][j] = __builtin_amdgcn_mfma_f32_16x16x32_bf16(aF[i], bF[j], acc[i][j], 0, 0, 0);
    __syncthreads();
  }

  float* base = dst + ks * (O_ * NTOT);
  int bb = n0 >> 12;       // batch (BN=128 divides 4096)
  int hw0 = n0 & 4095;
#pragma unroll
  for (int i = 0; i < 4; ++i) {
#pragma unroll
    for (int r = 0; r < 4; ++r) {
      int o = o0 + wm * 64 + i * 16 + q * 4 + r;
      float bv = withBias ? bias[o] : 0.f;
      float* orow = base + (bb * O_ + o) * HW + hw0;
#pragma unroll
      for (int j = 0; j < 4; ++j) orow[wn * 64 + j * 16 + lr] = acc[i][j][r] + bv;
    }
  }
}

// ---------------- K4: reduce 3 split-K partials + bias -> out ----------------
__global__ void k4_reduce(const float* __restrict__ part, const float* __restrict__ bias,
                          float* __restrict__ out) {
  int i4 = blockIdx.x * 256 + threadIdx.x;  // float4 index, total 1048576
  const f32x4* p0 = (const f32x4*)part;
  const f32x4* p1 = p0 + (O_ * NTOT / 4);
  const f32x4* p2 = p1 + (O_ * NTOT / 4);
  f32x4 a = p0[i4] + p1[i4] + p2[i4];
  int o = (i4 >> 10) & 255;  // 1024 float4 per o-row
  ((f32x4*)out)[i4] = a + bias[o];
}

extern "C" void kernel_launch(void* const* d_in, const int* in_sizes, int n_in,
                              void* d_out, int out_size, void* d_ws, size_t ws_size,
                              hipStream_t stream) {
  const float* x = (const float*)d_in[0];
  const float* w_om = (const float*)d_in[1];
  const float* b_om = (const float*)d_in[2];
  const float* weight = (const float*)d_in[3];
  const float* bias = (const float*)d_in[4];
  float* out = (float*)d_out;

  char* ws = (char*)d_ws;
  float* pypxmk = (float*)ws;                  // 442,368 f32 = 1,769,472 B
  uint16_t* wb = (uint16_t*)(ws + 1769472);    // 589,824 u16 = 1,179,648 B
  uint16_t* cols = (uint16_t*)(ws + 2949120);  // 37,748,736 u16 = 75,497,472 B
  float* part = (float*)(ws + 78446592);       // 3 x 16,777,216 B split-K partials

  hipLaunchKernelGGL(k0_wconv, dim3(2304), dim3(256), 0, stream, weight, wb);
  hipLaunchKernelGGL(k1_offconv, dim3(4 * 64 * 7), dim3(256), 0, stream, x, w_om, b_om, pypxmk);
  hipLaunchKernelGGL(k2_cols, dim3(4 * 64 * 8), dim3(256), 0, stream, x, pypxmk, cols);

  bool splitk = ws_size >= 128778240ull;
  if (splitk) {
    // 768 blocks = 3 blocks/CU (m97 sweet spot); bias applied in reduce
    hipLaunchKernelGGL(k3_gemm, dim3(768), dim3(256), 0, stream, wb, cols, bias, part, 24, 0);
    hipLaunchKernelGGL(k4_reduce, dim3(4096), dim3(256), 0, stream, part, bias, out);
  } else {
    hipLaunchKernelGGL(k3_gemm, dim3(256), dim3(256), 0, stream, wb, cols, bias, out, 72, 1);
  }
}

// Round 4
// 250.534 us; speedup vs baseline: 1.1909x; 1.1909x over previous
//
#include <hip/hip_runtime.h>
#include <stdint.h>

#define B_ 4
#define C_ 256
#define H_ 64
#define W_ 64
#define O_ 256
#define K_ 9
#define CK 2304     // K_*C_  (ck = k*256 + c, k-major)
#define HW 4096
#define NTOT 16384  // B_*HW

typedef __bf16 bf16x8 __attribute__((ext_vector_type(8)));
typedef float f32x4 __attribute__((ext_vector_type(4)));
typedef float f32x2 __attribute__((ext_vector_type(2)));
typedef f32x2 __attribute__((aligned(4))) f32x2u;  // 4B-aligned vector load

__device__ __forceinline__ uint16_t f2bf(float f) {
  uint32_t u = __builtin_bit_cast(uint32_t, f);
  return (uint16_t)((u + 0x7FFFu + ((u >> 16) & 1u)) >> 16);
}

__device__ __forceinline__ uint32_t pk_bf16(float a, float b) {
  uint16_t lo = __builtin_bit_cast(uint16_t, (__bf16)a);
  uint16_t hi = __builtin_bit_cast(uint16_t, (__bf16)b);
  return (uint32_t)lo | ((uint32_t)hi << 16);
}

// ---------------- K0: weight fp32 [O][C][3][3] -> bf16 wb[O][k*256+c] ----------------
__global__ void k0_wconv(const float* __restrict__ weight, uint16_t* __restrict__ wb) {
  int idx = blockIdx.x * 256 + threadIdx.x;
  if (idx >= O_ * CK) return;
  int o = idx / CK;
  int rem = idx - o * CK;
  int k = rem >> 8;
  int c = rem & 255;
  wb[idx] = f2bf(weight[(o * C_ + c) * K_ + k]);
}

// ---------------- K1: offset conv (fp32) -> py/px/mask [b][k][h][w] ----------------
__global__ void k1_offconv(const float* __restrict__ x, const float* __restrict__ w_om,
                           const float* __restrict__ b_om, float* __restrict__ pypxmk) {
  int bx = blockIdx.x;
  int jq = bx % 7;
  int h = (bx / 7) % H_;
  int b = bx / (7 * H_);
  int t = threadIdx.x;
  int w = t & 63;
  int cs = __builtin_amdgcn_readfirstlane(t >> 6);

  float acc[4] = {0.f, 0.f, 0.f, 0.f};
  const float* xb = x + (b * C_) * HW;

  for (int ci = 0; ci < 64; ++ci) {
    int c = cs * 64 + ci;
    const float* xr = xb + c * HW;
    float xv[3][3];
#pragma unroll
    for (int r = 0; r < 3; ++r) {
      int y = h - 1 + r;
      bool yv = ((unsigned)y < 64u);
#pragma unroll
      for (int dx = 0; dx < 3; ++dx) {
        int xx = w - 1 + dx;
        bool v = yv && ((unsigned)xx < 64u);
        xv[r][dx] = v ? xr[y * 64 + xx] : 0.f;
      }
    }
    const float* wp = w_om + ((jq * 4) * C_ + c) * 9;
#pragma unroll
    for (int jj = 0; jj < 4; ++jj) {
      int j = jq * 4 + jj;
      int jeff = (j < 27) ? jj : 0;  // jq=6,jj=3 is dead; avoid OOB read
      const float* wj = wp + jeff * (C_ * 9);
      float a = 0.f;
#pragma unroll
      for (int r = 0; r < 3; ++r)
#pragma unroll
        for (int dx = 0; dx < 3; ++dx)
          a = fmaf(xv[r][dx], wj[r * 3 + dx], a);
      acc[jj] += a;
    }
  }

  __shared__ float red[4][4][64];
#pragma unroll
  for (int jj = 0; jj < 4; ++jj) red[cs][jj][w] = acc[jj];
  __syncthreads();

  int jj = t >> 6;
  int j = jq * 4 + jj;
  if (j < 27) {
    float s = red[0][jj][w] + red[1][jj][w] + red[2][jj][w] + red[3][jj][w] + b_om[j];
    float* pyA = pypxmk;
    float* pxA = pypxmk + 147456;
    float* mkA = pypxmk + 294912;
    if (j < 18) {
      int k = j >> 1;
      int off = (b * 9 + k) * HW + h * 64 + w;
      if ((j & 1) == 0)
        pyA[off] = (float)(h - 1 + k / 3) + s;   // absolute sample y
      else
        pxA[off] = (float)(w - 1 + k % 3) + s;   // absolute sample x
    } else {
      int k = j - 18;
      mkA[(b * 9 + k) * HW + h * 64 + w] = 1.f / (1.f + __expf(-s));
    }
  }
}

// ---------------- K2: bilinear gather -> cols bf16 [b*hw][k*256+c] ----------------
// Grid = (b, h, cg): 4096 blocks; all 9 k's, one 16-channel group per block.
// LDS tile 18,688 B -> 8 blocks/CU (32 waves) for latency hiding.
// Per-k state (4 folded weights + 2 row offsets) is computed then consumed
// IMMEDIATELY (r3's 54-value live set caused scratch spills). Inner work per
// (k, c-pair): 4 float2 loads + 8 FMA + 1 packed LDS write — no cndmask.
__global__ void k2_cols(const float* __restrict__ x, const float* __restrict__ pypxmk,
                        uint16_t* __restrict__ cols) {
  int bx = blockIdx.x;
  int cg = bx & 15;
  int h = (bx >> 4) & 63;
  int b = bx >> 10;
  int t = threadIdx.x;
  int w = t & 63;
  int g = t >> 6;

  const float* pyA = pypxmk;
  const float* pxA = pypxmk + 147456;
  const float* mkA = pypxmk + 294912;

  __shared__ uint16_t tile[64 * 146];  // stride 73 dwords (odd) -> conflict-free
  const float* xb = x + b * C_ * HW;
  int cbase = cg * 16 + g * 4;

#pragma unroll
  for (int k = 0; k < 9; ++k) {
    int poff = (b * 9 + k) * HW + h * 64 + w;
    float py = pyA[poff];
    float px = pxA[poff];
    float mk = mkA[poff];
    float fy0 = floorf(py), fx0 = floorf(px);
    float ly = py - fy0, lx = px - fx0;
    int y0 = (int)fy0, x0 = (int)fx0;
    bool vy0 = ((unsigned)y0 < 64u), vy1 = ((unsigned)(y0 + 1) < 64u);
    bool vx0 = ((unsigned)x0 < 64u), vx1 = ((unsigned)(x0 + 1) < 64u);
    float w00 = (vy0 && vx0) ? (1.f - ly) * (1.f - lx) * mk : 0.f;
    float w01 = (vy0 && vx1) ? (1.f - ly) * lx * mk : 0.f;
    float w10 = (vy1 && vx0) ? ly * (1.f - lx) * mk : 0.f;
    float w11 = (vy1 && vx1) ? ly * lx * mk : 0.f;
    // float2 loaded at bx0=clamp(x0,0,62): fold the clamp-select into weights
    bool sel0 = (x0 >= 63);
    bool sel1 = (x0 >= 0);
    float wa0 = (sel0 ? 0.f : w00) + (sel1 ? 0.f : w01);
    float wb0 = (sel0 ? w00 : 0.f) + (sel1 ? w01 : 0.f);
    float wa1 = (sel0 ? 0.f : w10) + (sel1 ? 0.f : w11);
    float wb1 = (sel0 ? w10 : 0.f) + (sel1 ? w11 : 0.f);
    int bx0 = min(max(x0, 0), 62);
    int a0 = min(max(y0, 0), 63) * 64 + bx0;
    int a1 = min(max(y0 + 1, 0), 63) * 64 + bx0;

#pragma unroll
    for (int cp = 0; cp < 2; ++cp) {
      const float* xcA = xb + (cbase + cp * 2) * HW;
      const float* xcB = xcA + HW;
      f32x2 A0 = *(const f32x2u*)&xcA[a0];
      f32x2 A1 = *(const f32x2u*)&xcA[a1];
      f32x2 B0 = *(const f32x2u*)&xcB[a0];
      f32x2 B1 = *(const f32x2u*)&xcB[a1];
      float rA = wa0 * A0.x + wb0 * A0.y + wa1 * A1.x + wb1 * A1.y;
      float rB = wa0 * B0.x + wb0 * B0.y + wa1 * B1.x + wb1 * B1.y;
      *(uint32_t*)&tile[w * 146 + k * 16 + g * 4 + cp * 2] = pk_bf16(rA, rB);
    }
  }
  __syncthreads();

  // flush: 64 rows x 72 dwords = 4608 dwords; lane-consecutive u -> conflict-free
  // LDS reads (addr = u + wu, ~2 lanes/bank = free) and 32B-contiguous stores.
#pragma unroll
  for (int it = 0; it < 18; ++it) {
    int u = t + it * 256;
    int wu = u / 72;
    int rem = u - wu * 72;   // = k*8 + cd, cd in 0..7
    int k = rem >> 3;
    int cd = rem & 7;
    uint32_t val = *(const uint32_t*)&tile[wu * 146 + rem * 2];
    int n = b * HW + h * 64 + wu;
    int dst = n * CK + k * 256 + cg * 16 + cd * 2;
    *(uint32_t*)&cols[dst] = val;
  }
}

// ---------------- K3: GEMM dst[b][o][hw] (+)= wb[o][ck] . cols[n][ck] ----------------
// M=256, N=16384. 128x128 tile, BK=32, 4 waves (2x2), 16x16x32 bf16 MFMA.
// Split-K capable: grid = 256 * nsplit; block bx>>8 selects K-range and partial dst.
__global__ void k3_gemm(const uint16_t* __restrict__ wb, const uint16_t* __restrict__ cols,
                        const float* __restrict__ bias, float* __restrict__ dst,
                        int ktn, int withBias) {
  int bx = blockIdx.x;
  int ks = bx >> 8;
  int bxx = bx & 255;
  int mt = bxx & 1;
  int nt = bxx >> 1;
  int o0 = mt * 128;
  int n0 = nt * 128;
  int t = threadIdx.x;
  int lane = t & 63;
  int wid = t >> 6;
  int wm = wid >> 1, wn = wid & 1;
  int lr = lane & 15, q = lane >> 4;

  __shared__ __align__(16) uint16_t As[128 * 32];
  __shared__ __align__(16) uint16_t Bs[128 * 32];

  f32x4 acc[4][4];
  const f32x4 zero = {0.f, 0.f, 0.f, 0.f};
#pragma unroll
  for (int i = 0; i < 4; ++i)
#pragma unroll
    for (int j = 0; j < 4; ++j) acc[i][j] = zero;

  int r0 = t >> 2;          // 0..63: tile row this thread stages
  int koff = (t & 3) * 8;   // 8 bf16 = 16B per lane
  int kb = ks * ktn * 32;
  const uint16_t* gA = wb + (o0 + r0) * CK + kb + koff;
  const uint16_t* gB = cols + (n0 + r0) * CK + kb + koff;

  for (int kt = 0; kt < ktn; ++kt) {
    int k0 = kt * 32;
    __builtin_amdgcn_global_load_lds(
        (const __attribute__((address_space(1))) uint32_t*)(gA + k0),
        (__attribute__((address_space(3))) uint32_t*)&As[t * 8], 16, 0, 0);
    __builtin_amdgcn_global_load_lds(
        (const __attribute__((address_space(1))) uint32_t*)(gA + 64 * CK + k0),
        (__attribute__((address_space(3))) uint32_t*)&As[2048 + t * 8], 16, 0, 0);
    __builtin_amdgcn_global_load_lds(
        (const __attribute__((address_space(1))) uint32_t*)(gB + k0),
        (__attribute__((address_space(3))) uint32_t*)&Bs[t * 8], 16, 0, 0);
    __builtin_amdgcn_global_load_lds(
        (const __attribute__((address_space(1))) uint32_t*)(gB + 64 * CK + k0),
        (__attribute__((address_space(3))) uint32_t*)&Bs[2048 + t * 8], 16, 0, 0);
    __syncthreads();

    bf16x8 aF[4], bF[4];
#pragma unroll
    for (int i = 0; i < 4; ++i)
      aF[i] = *(const bf16x8*)&As[(wm * 64 + i * 16 + lr) * 32 + q * 8];
#pragma unroll
    for (int j = 0; j < 4; ++j)
      bF[j] = *(const bf16x8*)&Bs[(wn * 64 + j * 16 + lr) * 32 + q * 8];
#pragma unroll
    for (int i = 0; i < 4; ++i)
#pragma unroll
      for (int j = 0; j < 4; ++j)
        acc[i][j] = __builtin_amdgcn_mfma_f32_16x16x32_bf16(aF[i], bF[j], acc[i][j], 0, 0, 0);
    __syncthreads();
  }

  float* base = dst + ks * (O_ * NTOT);
  int bb = n0 >> 12;       // batch (BN=128 divides 4096)
  int hw0 = n0 & 4095;
#pragma unroll
  for (int i = 0; i < 4; ++i) {
#pragma unroll
    for (int r = 0; r < 4; ++r) {
      int o = o0 + wm * 64 + i * 16 + q * 4 + r;
      float bv = withBias ? bias[o] : 0.f;
      float* orow = base + (bb * O_ + o) * HW + hw0;
#pragma unroll
      for (int j = 0; j < 4; ++j) orow[wn * 64 + j * 16 + lr] = acc[i][j][r] + bv;
    }
  }
}

// ---------------- K4: reduce 3 split-K partials + bias -> out ----------------
__global__ void k4_reduce(const float* __restrict__ part, const float* __restrict__ bias,
                          float* __restrict__ out) {
  int i4 = blockIdx.x * 256 + threadIdx.x;  // float4 index, total 1048576
  const f32x4* p0 = (const f32x4*)part;
  const f32x4* p1 = p0 + (O_ * NTOT / 4);
  const f32x4* p2 = p1 + (O_ * NTOT / 4);
  f32x4 a = p0[i4] + p1[i4] + p2[i4];
  int o = (i4 >> 10) & 255;  // 1024 float4 per o-row
  ((f32x4*)out)[i4] = a + bias[o];
}

extern "C" void kernel_launch(void* const* d_in, const int* in_sizes, int n_in,
                              void* d_out, int out_size, void* d_ws, size_t ws_size,
                              hipStream_t stream) {
  const float* x = (const float*)d_in[0];
  const float* w_om = (const float*)d_in[1];
  const float* b_om = (const float*)d_in[2];
  const float* weight = (const float*)d_in[3];
  const float* bias = (const float*)d_in[4];
  float* out = (float*)d_out;

  char* ws = (char*)d_ws;
  float* pypxmk = (float*)ws;                  // 442,368 f32 = 1,769,472 B
  uint16_t* wb = (uint16_t*)(ws + 1769472);    // 589,824 u16 = 1,179,648 B
  uint16_t* cols = (uint16_t*)(ws + 2949120);  // 37,748,736 u16 = 75,497,472 B
  float* part = (float*)(ws + 78446592);       // 3 x 16,777,216 B split-K partials

  hipLaunchKernelGGL(k0_wconv, dim3(2304), dim3(256), 0, stream, weight, wb);
  hipLaunchKernelGGL(k1_offconv, dim3(4 * 64 * 7), dim3(256), 0, stream, x, w_om, b_om, pypxmk);
  hipLaunchKernelGGL(k2_cols, dim3(4 * 64 * 16), dim3(256), 0, stream, x, pypxmk, cols);

  bool splitk = ws_size >= 128778240ull;
  if (splitk) {
    // 768 blocks = 3 blocks/CU (m97 sweet spot); bias applied in reduce
    hipLaunchKernelGGL(k3_gemm, dim3(768), dim3(256), 0, stream, wb, cols, bias, part, 24, 0);
    hipLaunchKernelGGL(k4_reduce, dim3(4096), dim3(256), 0, stream, part, bias, out);
  } else {
    hipLaunchKernelGGL(k3_gemm, dim3(256), dim3(256), 0, stream, wb, cols, bias, out, 72, 1);
  }
}

// Round 5
// 208.708 us; speedup vs baseline: 1.4296x; 1.2004x over previous
//
#include <hip/hip_runtime.h>
#include <stdint.h>

#define B_ 4
#define C_ 256
#define H_ 64
#define W_ 64
#define O_ 256
#define K_ 9
#define CK 2304     // K_*C_  (ck = k*256 + c, k-major)
#define HW 4096
#define NTOT 16384  // B_*HW

typedef __bf16 bf16x8 __attribute__((ext_vector_type(8)));
typedef __bf16 bf16x4 __attribute__((ext_vector_type(4)));
typedef float f32x4 __attribute__((ext_vector_type(4)));
typedef float f32x2 __attribute__((ext_vector_type(2)));
typedef f32x2 __attribute__((aligned(4))) f32x2u;  // 4B-aligned vector load

__device__ __forceinline__ uint16_t f2bf(float f) {
  uint32_t u = __builtin_bit_cast(uint32_t, f);
  return (uint16_t)((u + 0x7FFFu + ((u >> 16) & 1u)) >> 16);
}

__device__ __forceinline__ uint32_t pk_bf16(float a, float b) {
  uint16_t lo = __builtin_bit_cast(uint16_t, (__bf16)a);
  uint16_t hi = __builtin_bit_cast(uint16_t, (__bf16)b);
  return (uint32_t)lo | ((uint32_t)hi << 16);
}

// ---------------- K0: weight fp32 [O][C][3][3] -> bf16 wb[O][k*256+c] ----------------
__global__ void k0_wconv(const float* __restrict__ weight, uint16_t* __restrict__ wb) {
  int idx = blockIdx.x * 256 + threadIdx.x;
  if (idx >= O_ * CK) return;
  int o = idx / CK;
  int rem = idx - o * CK;
  int k = rem >> 8;
  int c = rem & 255;
  wb[idx] = f2bf(weight[(o * C_ + c) * K_ + k]);
}

// ---------------- K1: offset conv (fp32) -> py/px/mask [b][k][h][w] ----------------
__global__ void k1_offconv(const float* __restrict__ x, const float* __restrict__ w_om,
                           const float* __restrict__ b_om, float* __restrict__ pypxmk) {
  int bx = blockIdx.x;
  int jq = bx % 7;
  int h = (bx / 7) % H_;
  int b = bx / (7 * H_);
  int t = threadIdx.x;
  int w = t & 63;
  int cs = __builtin_amdgcn_readfirstlane(t >> 6);

  float acc[4] = {0.f, 0.f, 0.f, 0.f};
  const float* xb = x + (b * C_) * HW;

  for (int ci = 0; ci < 64; ++ci) {
    int c = cs * 64 + ci;
    const float* xr = xb + c * HW;
    float xv[3][3];
#pragma unroll
    for (int r = 0; r < 3; ++r) {
      int y = h - 1 + r;
      bool yv = ((unsigned)y < 64u);
#pragma unroll
      for (int dx = 0; dx < 3; ++dx) {
        int xx = w - 1 + dx;
        bool v = yv && ((unsigned)xx < 64u);
        xv[r][dx] = v ? xr[y * 64 + xx] : 0.f;
      }
    }
    const float* wp = w_om + ((jq * 4) * C_ + c) * 9;
#pragma unroll
    for (int jj = 0; jj < 4; ++jj) {
      int j = jq * 4 + jj;
      int jeff = (j < 27) ? jj : 0;  // jq=6,jj=3 is dead; avoid OOB read
      const float* wj = wp + jeff * (C_ * 9);
      float a = 0.f;
#pragma unroll
      for (int r = 0; r < 3; ++r)
#pragma unroll
        for (int dx = 0; dx < 3; ++dx)
          a = fmaf(xv[r][dx], wj[r * 3 + dx], a);
      acc[jj] += a;
    }
  }

  __shared__ float red[4][4][64];
#pragma unroll
  for (int jj = 0; jj < 4; ++jj) red[cs][jj][w] = acc[jj];
  __syncthreads();

  int jj = t >> 6;
  int j = jq * 4 + jj;
  if (j < 27) {
    float s = red[0][jj][w] + red[1][jj][w] + red[2][jj][w] + red[3][jj][w] + b_om[j];
    float* pyA = pypxmk;
    float* pxA = pypxmk + 147456;
    float* mkA = pypxmk + 294912;
    if (j < 18) {
      int k = j >> 1;
      int off = (b * 9 + k) * HW + h * 64 + w;
      if ((j & 1) == 0)
        pyA[off] = (float)(h - 1 + k / 3) + s;   // absolute sample y
      else
        pxA[off] = (float)(w - 1 + k % 3) + s;   // absolute sample x
    } else {
      int k = j - 18;
      mkA[(b * 9 + k) * HW + h * 64 + w] = 1.f / (1.f + __expf(-s));
    }
  }
}

// ---------------- K2a: transpose x fp32 [b][c][hw] -> xT bf16 [b][hw][c] ----------------
// Grid = 4b x 64 hw-tiles x 4 c-tiles = 1024 blocks. 64x64 tile via LDS.
__global__ void k2a_xT(const float* __restrict__ x, uint16_t* __restrict__ xT) {
  int bx = blockIdx.x;
  int ct = bx & 3;
  int hwt = (bx >> 2) & 63;
  int b = bx >> 8;
  int t = threadIdx.x;
  int l = t & 63;
  int cq = t >> 6;

  __shared__ __align__(16) uint16_t tile[64 * 72];  // [hw][c], stride 72 u16 (16B-aligned rows)

  const float* xb = x + ((b * 256 + ct * 64) * HW) + hwt * 64;
#pragma unroll
  for (int i = 0; i < 16; ++i) {
    int c = cq * 16 + i;                    // local c 0..63
    tile[l * 72 + c] = f2bf(xb[c * HW + l]);
  }
  __syncthreads();

  int hw = t >> 2;
  int c8 = (t & 3) * 8;                     // two 8-u16 slices: c8 and c8+32
  uint16_t* dst = xT + ((size_t)b << 20) + (size_t)(hwt * 64 + hw) * 256 + ct * 64;
  *(uint4*)&dst[c8] = *(const uint4*)&tile[hw * 72 + c8];
  *(uint4*)&dst[c8 + 32] = *(const uint4*)&tile[hw * 72 + c8 + 32];
}

// ---------------- K2b: bilinear gather -> cols bf16 [n][k*256+c] ----------------
// One wave per (n,k) pair: p-loads and setup are wave-uniform (scalar); the 4
// corner-row reads are contiguous 512B wave segments of xT; output is one
// contiguous 512B wave store. No LDS, no barrier. Grid 2048 (8 blocks/CU),
// 18 pairs per wave.
__global__ void k2_cols(const uint16_t* __restrict__ xT, const float* __restrict__ pypxmk,
                        uint16_t* __restrict__ cols) {
  int bx = blockIdx.x;
  int g = __builtin_amdgcn_readfirstlane(threadIdx.x >> 6);
  int lane = threadIdx.x & 63;

  const float* pyA = pypxmk;
  const float* pxA = pypxmk + 147456;
  const float* mkA = pypxmk + 294912;

  for (int it = 0; it < 18; ++it) {
    int p = it * 4 + g;            // 0..71
    int pn = p / 9;
    int k = p - pn * 9;
    int n = (bx << 3) + pn;
    int b = n >> 12;
    int hw = n & 4095;
    int poff = (b * 9 + k) * HW + hw;
    float py = pyA[poff];
    float px = pxA[poff];
    float mk = mkA[poff];

    float fy0 = floorf(py), fx0 = floorf(px);
    float ly = py - fy0, lx = px - fx0;
    int y0 = (int)fy0, x0 = (int)fx0;
    bool vy0 = ((unsigned)y0 < 64u), vy1 = ((unsigned)(y0 + 1) < 64u);
    bool vx0 = ((unsigned)x0 < 64u), vx1 = ((unsigned)(x0 + 1) < 64u);
    float w00 = (vy0 && vx0) ? (1.f - ly) * (1.f - lx) * mk : 0.f;
    float w01 = (vy0 && vx1) ? (1.f - ly) * lx * mk : 0.f;
    float w10 = (vy1 && vx0) ? ly * (1.f - lx) * mk : 0.f;
    float w11 = (vy1 && vx1) ? ly * lx * mk : 0.f;
    // rows loaded at bx0=clamp(x0,0,62): fold the x-clamp select into weights
    bool sel0 = (x0 >= 63);
    bool sel1 = (x0 >= 0);
    float wa0 = (sel0 ? 0.f : w00) + (sel1 ? 0.f : w01);
    float wb0 = (sel0 ? w00 : 0.f) + (sel1 ? w01 : 0.f);
    float wa1 = (sel0 ? 0.f : w10) + (sel1 ? 0.f : w11);
    float wb1 = (sel0 ? w10 : 0.f) + (sel1 ? w11 : 0.f);
    int bx0 = min(max(x0, 0), 62);
    int a0 = min(max(y0, 0), 63) * 64 + bx0;
    int a1 = min(max(y0 + 1, 0), 63) * 64 + bx0;

    const uint16_t* xb = xT + ((size_t)b << 20);
    bf16x4 r00 = *(const bf16x4*)&xb[a0 * 256 + lane * 4];
    bf16x4 r01 = *(const bf16x4*)&xb[a0 * 256 + 256 + lane * 4];
    bf16x4 r10 = *(const bf16x4*)&xb[a1 * 256 + lane * 4];
    bf16x4 r11 = *(const bf16x4*)&xb[a1 * 256 + 256 + lane * 4];

    float v[4];
#pragma unroll
    for (int i = 0; i < 4; ++i)
      v[i] = wa0 * (float)r00[i] + wb0 * (float)r01[i] +
             wa1 * (float)r10[i] + wb1 * (float)r11[i];

    uint2 pk;
    pk.x = pk_bf16(v[0], v[1]);
    pk.y = pk_bf16(v[2], v[3]);
    *(uint2*)&cols[(size_t)n * CK + k * 256 + lane * 4] = pk;
  }
}

// ---------------- K2 fallback (r4 version) if ws can't hold xT ----------------
__global__ void k2_fb(const float* __restrict__ x, const float* __restrict__ pypxmk,
                      uint16_t* __restrict__ cols) {
  int bx = blockIdx.x;
  int cg = bx & 15;
  int h = (bx >> 4) & 63;
  int b = bx >> 10;
  int t = threadIdx.x;
  int w = t & 63;
  int g = t >> 6;

  const float* pyA = pypxmk;
  const float* pxA = pypxmk + 147456;
  const float* mkA = pypxmk + 294912;

  __shared__ uint16_t tile[64 * 146];
  const float* xb = x + b * C_ * HW;
  int cbase = cg * 16 + g * 4;

#pragma unroll
  for (int k = 0; k < 9; ++k) {
    int poff = (b * 9 + k) * HW + h * 64 + w;
    float py = pyA[poff];
    float px = pxA[poff];
    float mk = mkA[poff];
    float fy0 = floorf(py), fx0 = floorf(px);
    float ly = py - fy0, lx = px - fx0;
    int y0 = (int)fy0, x0 = (int)fx0;
    bool vy0 = ((unsigned)y0 < 64u), vy1 = ((unsigned)(y0 + 1) < 64u);
    bool vx0 = ((unsigned)x0 < 64u), vx1 = ((unsigned)(x0 + 1) < 64u);
    float w00 = (vy0 && vx0) ? (1.f - ly) * (1.f - lx) * mk : 0.f;
    float w01 = (vy0 && vx1) ? (1.f - ly) * lx * mk : 0.f;
    float w10 = (vy1 && vx0) ? ly * (1.f - lx) * mk : 0.f;
    float w11 = (vy1 && vx1) ? ly * lx * mk : 0.f;
    bool sel0 = (x0 >= 63);
    bool sel1 = (x0 >= 0);
    float wa0 = (sel0 ? 0.f : w00) + (sel1 ? 0.f : w01);
    float wb0 = (sel0 ? w00 : 0.f) + (sel1 ? w01 : 0.f);
    float wa1 = (sel0 ? 0.f : w10) + (sel1 ? 0.f : w11);
    float wb1 = (sel0 ? w10 : 0.f) + (sel1 ? w11 : 0.f);
    int bx0 = min(max(x0, 0), 62);
    int a0 = min(max(y0, 0), 63) * 64 + bx0;
    int a1 = min(max(y0 + 1, 0), 63) * 64 + bx0;

#pragma unroll
    for (int cp = 0; cp < 2; ++cp) {
      const float* xcA = xb + (cbase + cp * 2) * HW;
      const float* xcB = xcA + HW;
      f32x2 A0 = *(const f32x2u*)&xcA[a0];
      f32x2 A1 = *(const f32x2u*)&xcA[a1];
      f32x2 B0 = *(const f32x2u*)&xcB[a0];
      f32x2 B1 = *(const f32x2u*)&xcB[a1];
      float rA = wa0 * A0.x + wb0 * A0.y + wa1 * A1.x + wb1 * A1.y;
      float rB = wa0 * B0.x + wb0 * B0.y + wa1 * B1.x + wb1 * B1.y;
      *(uint32_t*)&tile[w * 146 + k * 16 + g * 4 + cp * 2] = pk_bf16(rA, rB);
    }
  }
  __syncthreads();

#pragma unroll
  for (int it = 0; it < 18; ++it) {
    int u = t + it * 256;
    int wu = u / 72;
    int rem = u - wu * 72;
    int k = rem >> 3;
    int cd = rem & 7;
    uint32_t val = *(const uint32_t*)&tile[wu * 146 + rem * 2];
    int n = b * HW + h * 64 + wu;
    int dst = n * CK + k * 256 + cg * 16 + cd * 2;
    *(uint32_t*)&cols[dst] = val;
  }
}

// ---------------- K3: GEMM dst[b][o][hw] (+)= wb[o][ck] . cols[n][ck] ----------------
__global__ void k3_gemm(const uint16_t* __restrict__ wb, const uint16_t* __restrict__ cols,
                        const float* __restrict__ bias, float* __restrict__ dst,
                        int ktn, int withBias) {
  int bx = blockIdx.x;
  int ks = bx >> 8;
  int bxx = bx & 255;
  int mt = bxx & 1;
  int nt = bxx >> 1;
  int o0 = mt * 128;
  int n0 = nt * 128;
  int t = threadIdx.x;
  int lane = t & 63;
  int wid = t >> 6;
  int wm = wid >> 1, wn = wid & 1;
  int lr = lane & 15, q = lane >> 4;

  __shared__ __align__(16) uint16_t As[128 * 32];
  __shared__ __align__(16) uint16_t Bs[128 * 32];

  f32x4 acc[4][4];
  const f32x4 zero = {0.f, 0.f, 0.f, 0.f};
#pragma unroll
  for (int i = 0; i < 4; ++i)
#pragma unroll
    for (int j = 0; j < 4; ++j) acc[i][j] = zero;

  int r0 = t >> 2;
  int koff = (t & 3) * 8;
  int kb = ks * ktn * 32;
  const uint16_t* gA = wb + (o0 + r0) * CK + kb + koff;
  const uint16_t* gB = cols + (n0 + r0) * CK + kb + koff;

  for (int kt = 0; kt < ktn; ++kt) {
    int k0 = kt * 32;
    __builtin_amdgcn_global_load_lds(
        (const __attribute__((address_space(1))) uint32_t*)(gA + k0),
        (__attribute__((address_space(3))) uint32_t*)&As[t * 8], 16, 0, 0);
    __builtin_amdgcn_global_load_lds(
        (const __attribute__((address_space(1))) uint32_t*)(gA + 64 * CK + k0),
        (__attribute__((address_space(3))) uint32_t*)&As[2048 + t * 8], 16, 0, 0);
    __builtin_amdgcn_global_load_lds(
        (const __attribute__((address_space(1))) uint32_t*)(gB + k0),
        (__attribute__((address_space(3))) uint32_t*)&Bs[t * 8], 16, 0, 0);
    __builtin_amdgcn_global_load_lds(
        (const __attribute__((address_space(1))) uint32_t*)(gB + 64 * CK + k0),
        (__attribute__((address_space(3))) uint32_t*)&Bs[2048 + t * 8], 16, 0, 0);
    __syncthreads();

    bf16x8 aF[4], bF[4];
#pragma unroll
    for (int i = 0; i < 4; ++i)
      aF[i] = *(const bf16x8*)&As[(wm * 64 + i * 16 + lr) * 32 + q * 8];
#pragma unroll
    for (int j = 0; j < 4; ++j)
      bF[j] = *(const bf16x8*)&Bs[(wn * 64 + j * 16 + lr) * 32 + q * 8];
#pragma unroll
    for (int i = 0; i < 4; ++i)
#pragma unroll
      for (int j = 0; j < 4; ++j)
        acc[i][j] = __builtin_amdgcn_mfma_f32_16x16x32_bf16(aF[i], bF[j], acc[i][j], 0, 0, 0);
    __syncthreads();
  }

  float* base = dst + ks * (O_ * NTOT);
  int bb = n0 >> 12;
  int hw0 = n0 & 4095;
#pragma unroll
  for (int i = 0; i < 4; ++i) {
#pragma unroll
    for (int r = 0; r < 4; ++r) {
      int o = o0 + wm * 64 + i * 16 + q * 4 + r;
      float bv = withBias ? bias[o] : 0.f;
      float* orow = base + (bb * O_ + o) * HW + hw0;
#pragma unroll
      for (int j = 0; j < 4; ++j) orow[wn * 64 + j * 16 + lr] = acc[i][j][r] + bv;
    }
  }
}

// ---------------- K4: reduce 3 split-K partials + bias -> out ----------------
__global__ void k4_reduce(const float* __restrict__ part, const float* __restrict__ bias,
                          float* __restrict__ out) {
  int i4 = blockIdx.x * 256 + threadIdx.x;
  const f32x4* p0 = (const f32x4*)part;
  const f32x4* p1 = p0 + (O_ * NTOT / 4);
  const f32x4* p2 = p1 + (O_ * NTOT / 4);
  f32x4 a = p0[i4] + p1[i4] + p2[i4];
  int o = (i4 >> 10) & 255;
  ((f32x4*)out)[i4] = a + bias[o];
}

extern "C" void kernel_launch(void* const* d_in, const int* in_sizes, int n_in,
                              void* d_out, int out_size, void* d_ws, size_t ws_size,
                              hipStream_t stream) {
  const float* x = (const float*)d_in[0];
  const float* w_om = (const float*)d_in[1];
  const float* b_om = (const float*)d_in[2];
  const float* weight = (const float*)d_in[3];
  const float* bias = (const float*)d_in[4];
  float* out = (float*)d_out;

  char* ws = (char*)d_ws;
  float* pypxmk = (float*)ws;                  // 1,769,472 B
  uint16_t* wb = (uint16_t*)(ws + 1769472);    // 1,179,648 B
  uint16_t* cols = (uint16_t*)(ws + 2949120);  // 75,497,472 B -> end 78,446,592
  uint16_t* xT = (uint16_t*)(ws + 78446592);   // 8,388,608 B  -> end 86,835,200
  float* part = (float*)(ws + 86835200);       // 50,331,648 B -> end 137,166,848

  bool xtpath = ws_size >= 86835200ull;
  bool splitk = ws_size >= 137166848ull;

  hipLaunchKernelGGL(k0_wconv, dim3(2304), dim3(256), 0, stream, weight, wb);
  hipLaunchKernelGGL(k1_offconv, dim3(4 * 64 * 7), dim3(256), 0, stream, x, w_om, b_om, pypxmk);

  if (xtpath) {
    hipLaunchKernelGGL(k2a_xT, dim3(1024), dim3(256), 0, stream, x, xT);
    hipLaunchKernelGGL(k2_cols, dim3(2048), dim3(256), 0, stream, xT, pypxmk, cols);
  } else {
    hipLaunchKernelGGL(k2_fb, dim3(4 * 64 * 16), dim3(256), 0, stream, x, pypxmk, cols);
  }

  if (splitk) {
    hipLaunchKernelGGL(k3_gemm, dim3(768), dim3(256), 0, stream, wb, cols, bias, part, 24, 0);
    hipLaunchKernelGGL(k4_reduce, dim3(4096), dim3(256), 0, stream, part, bias, out);
  } else {
    hipLaunchKernelGGL(k3_gemm, dim3(256), dim3(256), 0, stream, wb, cols, bias, out, 72, 1);
  }
}

// Round 6
// 180.450 us; speedup vs baseline: 1.6534x; 1.1566x over previous
//
#include <hip/hip_runtime.h>
#include <stdint.h>

#define B_ 4
#define C_ 256
#define H_ 64
#define W_ 64
#define O_ 256
#define K_ 9
#define CK 2304     // K_*C_  (ck = k*256 + c, k-major)
#define HW 4096
#define NTOT 16384  // B_*HW

typedef __bf16 bf16x8 __attribute__((ext_vector_type(8)));
typedef __bf16 bf16x4 __attribute__((ext_vector_type(4)));
typedef float f32x4 __attribute__((ext_vector_type(4)));
typedef float f32x2 __attribute__((ext_vector_type(2)));
typedef f32x2 __attribute__((aligned(4))) f32x2u;

__device__ __forceinline__ uint16_t f2bf(float f) {
  uint32_t u = __builtin_bit_cast(uint32_t, f);
  return (uint16_t)((u + 0x7FFFu + ((u >> 16) & 1u)) >> 16);
}

__device__ __forceinline__ uint32_t pk_bf16(float a, float b) {
  uint16_t lo = __builtin_bit_cast(uint16_t, (__bf16)a);
  uint16_t hi = __builtin_bit_cast(uint16_t, (__bf16)b);
  return (uint32_t)lo | ((uint32_t)hi << 16);
}

// ---------------- K0: weight fp32 [O][C][3][3] -> bf16 wb[O][k*256+c] ----------------
__global__ void k0_wconv(const float* __restrict__ weight, uint16_t* __restrict__ wb) {
  int idx = blockIdx.x * 256 + threadIdx.x;
  if (idx >= O_ * CK) return;
  int o = idx / CK;
  int rem = idx - o * CK;
  int k = rem >> 8;
  int c = rem & 255;
  wb[idx] = f2bf(weight[(o * C_ + c) * K_ + k]);
}

// ------------- K0b: w_om fp32 [27][256][3][3] -> bf16 womb[32][k*256+c], rows 27..31 = 0 ----
__global__ void k0b_womb(const float* __restrict__ w_om, uint16_t* __restrict__ womb) {
  int idx = blockIdx.x * 256 + threadIdx.x;  // 32*2304 = 73728
  if (idx >= 32 * CK) return;
  int j = idx / CK;
  int ck = idx - j * CK;
  int k = ck >> 8, c = ck & 255;
  womb[idx] = (j < 27) ? f2bf(w_om[(j * 256 + c) * 9 + k]) : (uint16_t)0;
}

// ---------------- K2a: transpose x fp32 [b][c][hw] -> xT bf16 [b][hw][c] ----------------
__global__ void k2a_xT(const float* __restrict__ x, uint16_t* __restrict__ xT) {
  int bx = blockIdx.x;
  int ct = bx & 3;
  int hwt = (bx >> 2) & 63;
  int b = bx >> 8;
  int t = threadIdx.x;
  int l = t & 63;
  int cq = t >> 6;

  __shared__ __align__(16) uint16_t tile[64 * 72];

  const float* xb = x + ((b * 256 + ct * 64) * HW) + hwt * 64;
#pragma unroll
  for (int i = 0; i < 16; ++i) {
    int c = cq * 16 + i;
    tile[l * 72 + c] = f2bf(xb[c * HW + l]);
  }
  __syncthreads();

  int hw = t >> 2;
  int c8 = (t & 3) * 8;
  uint16_t* dst = xT + ((size_t)b << 20) + (size_t)(hwt * 64 + hw) * 256 + ct * 64;
  *(uint4*)&dst[c8] = *(const uint4*)&tile[hw * 72 + c8];
  *(uint4*)&dst[c8 + 32] = *(const uint4*)&tile[hw * 72 + c8 + 32];
}

// ---------------- K1: offset conv as MFMA GEMM om[32][16384] = womb . im2col(xT) -------
// Grid = 256 n-tiles(64) x ksplit 3 (3 kernel positions each) = 768 blocks.
// B-fragments read DIRECTLY from xT (integer-shifted rows, contiguous in c);
// out-of-bounds rows redirect to womb's zero rows (pointer cndmask, once per k).
// No LDS, no barrier. Partials [ks][32][16384] fp32 -> k1b.
__global__ void k1_mfma(const uint16_t* __restrict__ womb, const uint16_t* __restrict__ xT,
                        float* __restrict__ ompart) {
  int bx = blockIdx.x;
  int ks = bx >> 8;          // 0..2
  int nt = bx & 255;
  int t = threadIdx.x;
  int lane = t & 63;
  int wid = t >> 6;
  int lr = lane & 15, q = lane >> 4;
  int n = nt * 64 + wid * 16 + lr;
  int b = n >> 12;
  int hw = n & 4095;
  int y = hw >> 6, xx = hw & 63;
  const uint16_t* xb = xT + ((size_t)b << 20);
  const uint16_t* zrow = womb + 31 * CK;  // 2304 zeros

  f32x4 acc0 = {0.f, 0.f, 0.f, 0.f};
  f32x4 acc1 = {0.f, 0.f, 0.f, 0.f};

  for (int kk = 0; kk < 3; ++kk) {
    int k = ks * 3 + kk;
    int dy = k / 3, dx = k - dy * 3;
    int ny = y + dy - 1, nx = xx + dx - 1;
    bool valid = ((unsigned)ny < 64u) && ((unsigned)nx < 64u);
    int row = (min(max(ny, 0), 63) << 6) + min(max(nx, 0), 63);
    const uint16_t* bp = valid ? (xb + row * 256 + q * 8) : (zrow + q * 8);
    const uint16_t* ap = womb + lr * CK + k * 256 + q * 8;
#pragma unroll
    for (int kt = 0; kt < 8; ++kt) {
      int c0 = kt * 32;
      bf16x8 bF = *(const bf16x8*)&bp[c0];
      bf16x8 aF0 = *(const bf16x8*)&ap[c0];
      bf16x8 aF1 = *(const bf16x8*)&ap[16 * CK + c0];
      acc0 = __builtin_amdgcn_mfma_f32_16x16x32_bf16(aF0, bF, acc0, 0, 0, 0);
      acc1 = __builtin_amdgcn_mfma_f32_16x16x32_bf16(aF1, bF, acc1, 0, 0, 0);
    }
  }

  float* op = ompart + ks * (32 * NTOT);
#pragma unroll
  for (int r = 0; r < 4; ++r) {
    op[(q * 4 + r) * NTOT + n] = acc0[r];
    op[(16 + q * 4 + r) * NTOT + n] = acc1[r];
  }
}

// ---------------- K1b: reduce 3 partials + b_om -> py/px/mask [b][k][hw] ----------------
__global__ void k1b_ppm(const float* __restrict__ ompart, const float* __restrict__ b_om,
                        float* __restrict__ pypxmk) {
  int tid = blockIdx.x * 256 + threadIdx.x;  // 9*16384 = 147456
  int k = tid >> 14;
  int n = tid & 16383;
  int b = n >> 12;
  int hw = n & 4095;
  int h = hw >> 6, w = hw & 63;
  const float* p0 = ompart;
  const float* p1 = ompart + 32 * NTOT;
  const float* p2 = ompart + 64 * NTOT;
  int iy = (2 * k) * NTOT + n;
  int ix = (2 * k + 1) * NTOT + n;
  int im = (18 + k) * NTOT + n;
  float oy = p0[iy] + p1[iy] + p2[iy] + b_om[2 * k];
  float ox = p0[ix] + p1[ix] + p2[ix] + b_om[2 * k + 1];
  float m = p0[im] + p1[im] + p2[im] + b_om[18 + k];
  int off = (b * 9 + k) * HW + hw;
  pypxmk[off] = (float)(h - 1 + k / 3) + oy;
  pypxmk[147456 + off] = (float)(w - 1 + k % 3) + ox;
  pypxmk[294912 + off] = 1.f / (1.f + __expf(-m));
}

// ---------------- K1 fallback: fp32 direct conv (if ws too small for MFMA path) --------
__global__ void k1_offconv(const float* __restrict__ x, const float* __restrict__ w_om,
                           const float* __restrict__ b_om, float* __restrict__ pypxmk) {
  int bx = blockIdx.x;
  int jq = bx % 7;
  int h = (bx / 7) % H_;
  int b = bx / (7 * H_);
  int t = threadIdx.x;
  int w = t & 63;
  int cs = __builtin_amdgcn_readfirstlane(t >> 6);

  float acc[4] = {0.f, 0.f, 0.f, 0.f};
  const float* xb = x + (b * C_) * HW;

  for (int ci = 0; ci < 64; ++ci) {
    int c = cs * 64 + ci;
    const float* xr = xb + c * HW;
    float xv[3][3];
#pragma unroll
    for (int r = 0; r < 3; ++r) {
      int y = h - 1 + r;
      bool yv = ((unsigned)y < 64u);
#pragma unroll
      for (int dx = 0; dx < 3; ++dx) {
        int xx = w - 1 + dx;
        bool v = yv && ((unsigned)xx < 64u);
        xv[r][dx] = v ? xr[y * 64 + xx] : 0.f;
      }
    }
    const float* wp = w_om + ((jq * 4) * C_ + c) * 9;
#pragma unroll
    for (int jj = 0; jj < 4; ++jj) {
      int j = jq * 4 + jj;
      int jeff = (j < 27) ? jj : 0;
      const float* wj = wp + jeff * (C_ * 9);
      float a = 0.f;
#pragma unroll
      for (int r = 0; r < 3; ++r)
#pragma unroll
        for (int dx = 0; dx < 3; ++dx)
          a = fmaf(xv[r][dx], wj[r * 3 + dx], a);
      acc[jj] += a;
    }
  }

  __shared__ float red[4][4][64];
#pragma unroll
  for (int jj = 0; jj < 4; ++jj) red[cs][jj][w] = acc[jj];
  __syncthreads();

  int jj = t >> 6;
  int j = jq * 4 + jj;
  if (j < 27) {
    float s = red[0][jj][w] + red[1][jj][w] + red[2][jj][w] + red[3][jj][w] + b_om[j];
    float* pyA = pypxmk;
    float* pxA = pypxmk + 147456;
    float* mkA = pypxmk + 294912;
    if (j < 18) {
      int k = j >> 1;
      int off = (b * 9 + k) * HW + h * 64 + w;
      if ((j & 1) == 0)
        pyA[off] = (float)(h - 1 + k / 3) + s;
      else
        pxA[off] = (float)(w - 1 + k % 3) + s;
    } else {
      int k = j - 18;
      mkA[(b * 9 + k) * HW + h * 64 + w] = 1.f / (1.f + __expf(-s));
    }
  }
}

// ---------------- K2b: bilinear gather -> cols bf16 [n][k*256+c] ----------------
__global__ void k2_cols(const uint16_t* __restrict__ xT, const float* __restrict__ pypxmk,
                        uint16_t* __restrict__ cols) {
  int bx = blockIdx.x;
  int g = __builtin_amdgcn_readfirstlane(threadIdx.x >> 6);
  int lane = threadIdx.x & 63;

  const float* pyA = pypxmk;
  const float* pxA = pypxmk + 147456;
  const float* mkA = pypxmk + 294912;

  for (int it = 0; it < 18; ++it) {
    int p = it * 4 + g;
    int pn = p / 9;
    int k = p - pn * 9;
    int n = (bx << 3) + pn;
    int b = n >> 12;
    int hw = n & 4095;
    int poff = (b * 9 + k) * HW + hw;
    float py = pyA[poff];
    float px = pxA[poff];
    float mk = mkA[poff];

    float fy0 = floorf(py), fx0 = floorf(px);
    float ly = py - fy0, lx = px - fx0;
    int y0 = (int)fy0, x0 = (int)fx0;
    bool vy0 = ((unsigned)y0 < 64u), vy1 = ((unsigned)(y0 + 1) < 64u);
    bool vx0 = ((unsigned)x0 < 64u), vx1 = ((unsigned)(x0 + 1) < 64u);
    float w00 = (vy0 && vx0) ? (1.f - ly) * (1.f - lx) * mk : 0.f;
    float w01 = (vy0 && vx1) ? (1.f - ly) * lx * mk : 0.f;
    float w10 = (vy1 && vx0) ? ly * (1.f - lx) * mk : 0.f;
    float w11 = (vy1 && vx1) ? ly * lx * mk : 0.f;
    bool sel0 = (x0 >= 63);
    bool sel1 = (x0 >= 0);
    float wa0 = (sel0 ? 0.f : w00) + (sel1 ? 0.f : w01);
    float wb0 = (sel0 ? w00 : 0.f) + (sel1 ? w01 : 0.f);
    float wa1 = (sel0 ? 0.f : w10) + (sel1 ? 0.f : w11);
    float wb1 = (sel0 ? w10 : 0.f) + (sel1 ? w11 : 0.f);
    int bx0 = min(max(x0, 0), 62);
    int a0 = min(max(y0, 0), 63) * 64 + bx0;
    int a1 = min(max(y0 + 1, 0), 63) * 64 + bx0;

    const uint16_t* xb = xT + ((size_t)b << 20);
    bf16x4 r00 = *(const bf16x4*)&xb[a0 * 256 + lane * 4];
    bf16x4 r01 = *(const bf16x4*)&xb[a0 * 256 + 256 + lane * 4];
    bf16x4 r10 = *(const bf16x4*)&xb[a1 * 256 + lane * 4];
    bf16x4 r11 = *(const bf16x4*)&xb[a1 * 256 + 256 + lane * 4];

    float v[4];
#pragma unroll
    for (int i = 0; i < 4; ++i)
      v[i] = wa0 * (float)r00[i] + wb0 * (float)r01[i] +
             wa1 * (float)r10[i] + wb1 * (float)r11[i];

    uint2 pk;
    pk.x = pk_bf16(v[0], v[1]);
    pk.y = pk_bf16(v[2], v[3]);
    *(uint2*)&cols[(size_t)n * CK + k * 256 + lane * 4] = pk;
  }
}

// ---------------- K2 fallback (fp32 x path) ----------------
__global__ void k2_fb(const float* __restrict__ x, const float* __restrict__ pypxmk,
                      uint16_t* __restrict__ cols) {
  int bx = blockIdx.x;
  int cg = bx & 15;
  int h = (bx >> 4) & 63;
  int b = bx >> 10;
  int t = threadIdx.x;
  int w = t & 63;
  int g = t >> 6;

  const float* pyA = pypxmk;
  const float* pxA = pypxmk + 147456;
  const float* mkA = pypxmk + 294912;

  __shared__ uint16_t tile[64 * 146];
  const float* xb = x + b * C_ * HW;
  int cbase = cg * 16 + g * 4;

#pragma unroll
  for (int k = 0; k < 9; ++k) {
    int poff = (b * 9 + k) * HW + h * 64 + w;
    float py = pyA[poff];
    float px = pxA[poff];
    float mk = mkA[poff];
    float fy0 = floorf(py), fx0 = floorf(px);
    float ly = py - fy0, lx = px - fx0;
    int y0 = (int)fy0, x0 = (int)fx0;
    bool vy0 = ((unsigned)y0 < 64u), vy1 = ((unsigned)(y0 + 1) < 64u);
    bool vx0 = ((unsigned)x0 < 64u), vx1 = ((unsigned)(x0 + 1) < 64u);
    float w00 = (vy0 && vx0) ? (1.f - ly) * (1.f - lx) * mk : 0.f;
    float w01 = (vy0 && vx1) ? (1.f - ly) * lx * mk : 0.f;
    float w10 = (vy1 && vx0) ? ly * (1.f - lx) * mk : 0.f;
    float w11 = (vy1 && vx1) ? ly * lx * mk : 0.f;
    bool sel0 = (x0 >= 63);
    bool sel1 = (x0 >= 0);
    float wa0 = (sel0 ? 0.f : w00) + (sel1 ? 0.f : w01);
    float wb0 = (sel0 ? w00 : 0.f) + (sel1 ? w01 : 0.f);
    float wa1 = (sel0 ? 0.f : w10) + (sel1 ? 0.f : w11);
    float wb1 = (sel0 ? w10 : 0.f) + (sel1 ? w11 : 0.f);
    int bx0 = min(max(x0, 0), 62);
    int a0 = min(max(y0, 0), 63) * 64 + bx0;
    int a1 = min(max(y0 + 1, 0), 63) * 64 + bx0;

#pragma unroll
    for (int cp = 0; cp < 2; ++cp) {
      const float* xcA = xb + (cbase + cp * 2) * HW;
      const float* xcB = xcA + HW;
      f32x2 A0 = *(const f32x2u*)&xcA[a0];
      f32x2 A1 = *(const f32x2u*)&xcA[a1];
      f32x2 B0 = *(const f32x2u*)&xcB[a0];
      f32x2 B1 = *(const f32x2u*)&xcB[a1];
      float rA = wa0 * A0.x + wb0 * A0.y + wa1 * A1.x + wb1 * A1.y;
      float rB = wa0 * B0.x + wb0 * B0.y + wa1 * B1.x + wb1 * B1.y;
      *(uint32_t*)&tile[w * 146 + k * 16 + g * 4 + cp * 2] = pk_bf16(rA, rB);
    }
  }
  __syncthreads();

#pragma unroll
  for (int it = 0; it < 18; ++it) {
    int u = t + it * 256;
    int wu = u / 72;
    int rem = u - wu * 72;
    int k = rem >> 3;
    int cd = rem & 7;
    uint32_t val = *(const uint32_t*)&tile[wu * 146 + rem * 2];
    int n = b * HW + h * 64 + wu;
    int dst = n * CK + k * 256 + cg * 16 + cd * 2;
    *(uint32_t*)&cols[dst] = val;
  }
}

// ---------------- K3: GEMM dst[b][o][hw] (+)= wb[o][ck] . cols[n][ck] ----------------
__global__ void k3_gemm(const uint16_t* __restrict__ wb, const uint16_t* __restrict__ cols,
                        const float* __restrict__ bias, float* __restrict__ dst,
                        int ktn, int withBias) {
  int bx = blockIdx.x;
  int ks = bx >> 8;
  int bxx = bx & 255;
  int mt = bxx & 1;
  int nt = bxx >> 1;
  int o0 = mt * 128;
  int n0 = nt * 128;
  int t = threadIdx.x;
  int lane = t & 63;
  int wid = t >> 6;
  int wm = wid >> 1, wn = wid & 1;
  int lr = lane & 15, q = lane >> 4;

  __shared__ __align__(16) uint16_t As[128 * 32];
  __shared__ __align__(16) uint16_t Bs[128 * 32];

  f32x4 acc[4][4];
  const f32x4 zero = {0.f, 0.f, 0.f, 0.f};
#pragma unroll
  for (int i = 0; i < 4; ++i)
#pragma unroll
    for (int j = 0; j < 4; ++j) acc[i][j] = zero;

  int r0 = t >> 2;
  int koff = (t & 3) * 8;
  int kb = ks * ktn * 32;
  const uint16_t* gA = wb + (o0 + r0) * CK + kb + koff;
  const uint16_t* gB = cols + (n0 + r0) * CK + kb + koff;

  for (int kt = 0; kt < ktn; ++kt) {
    int k0 = kt * 32;
    __builtin_amdgcn_global_load_lds(
        (const __attribute__((address_space(1))) uint32_t*)(gA + k0),
        (__attribute__((address_space(3))) uint32_t*)&As[t * 8], 16, 0, 0);
    __builtin_amdgcn_global_load_lds(
        (const __attribute__((address_space(1))) uint32_t*)(gA + 64 * CK + k0),
        (__attribute__((address_space(3))) uint32_t*)&As[2048 + t * 8], 16, 0, 0);
    __builtin_amdgcn_global_load_lds(
        (const __attribute__((address_space(1))) uint32_t*)(gB + k0),
        (__attribute__((address_space(3))) uint32_t*)&Bs[t * 8], 16, 0, 0);
    __builtin_amdgcn_global_load_lds(
        (const __attribute__((address_space(1))) uint32_t*)(gB + 64 * CK + k0),
        (__attribute__((address_space(3))) uint32_t*)&Bs[2048 + t * 8], 16, 0, 0);
    __syncthreads();

    bf16x8 aF[4], bF[4];
#pragma unroll
    for (int i = 0; i < 4; ++i)
      aF[i] = *(const bf16x8*)&As[(wm * 64 + i * 16 + lr) * 32 + q * 8];
#pragma unroll
    for (int j = 0; j < 4; ++j)
      bF[j] = *(const bf16x8*)&Bs[(wn * 64 + j * 16 + lr) * 32 + q * 8];
#pragma unroll
    for (int i = 0; i < 4; ++i)
#pragma unroll
      for (int j = 0; j < 4; ++j)
        acc[i][j] = __builtin_amdgcn_mfma_f32_16x16x32_bf16(aF[i], bF[j], acc[i][j], 0, 0, 0);
    __syncthreads();
  }

  float* base = dst + ks * (O_ * NTOT);
  int bb = n0 >> 12;
  int hw0 = n0 & 4095;
#pragma unroll
  for (int i = 0; i < 4; ++i) {
#pragma unroll
    for (int r = 0; r < 4; ++r) {
      int o = o0 + wm * 64 + i * 16 + q * 4 + r;
      float bv = withBias ? bias[o] : 0.f;
      float* orow = base + (bb * O_ + o) * HW + hw0;
#pragma unroll
      for (int j = 0; j < 4; ++j) orow[wn * 64 + j * 16 + lr] = acc[i][j][r] + bv;
    }
  }
}

// ---------------- K4: reduce 3 split-K partials + bias -> out ----------------
__global__ void k4_reduce(const float* __restrict__ part, const float* __restrict__ bias,
                          float* __restrict__ out) {
  int i4 = blockIdx.x * 256 + threadIdx.x;
  const f32x4* p0 = (const f32x4*)part;
  const f32x4* p1 = p0 + (O_ * NTOT / 4);
  const f32x4* p2 = p1 + (O_ * NTOT / 4);
  f32x4 a = p0[i4] + p1[i4] + p2[i4];
  int o = (i4 >> 10) & 255;
  ((f32x4*)out)[i4] = a + bias[o];
}

extern "C" void kernel_launch(void* const* d_in, const int* in_sizes, int n_in,
                              void* d_out, int out_size, void* d_ws, size_t ws_size,
                              hipStream_t stream) {
  const float* x = (const float*)d_in[0];
  const float* w_om = (const float*)d_in[1];
  const float* b_om = (const float*)d_in[2];
  const float* weight = (const float*)d_in[3];
  const float* bias = (const float*)d_in[4];
  float* out = (float*)d_out;

  char* ws = (char*)d_ws;
  float* pypxmk = (float*)ws;                   // 1,769,472 B
  uint16_t* wb = (uint16_t*)(ws + 1769472);     // 1,179,648 B
  uint16_t* cols = (uint16_t*)(ws + 2949120);   // 75,497,472 B -> 78,446,592
  uint16_t* xT = (uint16_t*)(ws + 78446592);    // 8,388,608 B  -> 86,835,200
  uint16_t* womb = (uint16_t*)(ws + 86835200);  // 147,456 B    -> 86,982,656
  float* ompart = (float*)(ws + 86982656);      // 6,291,456 B  -> 93,274,112
  float* part = (float*)(ws + 93274112);        // 50,331,648 B -> 143,605,760

  bool xtpath = ws_size >= 86835200ull;
  bool mfmak1 = ws_size >= 93274112ull;
  bool splitk = ws_size >= 143605760ull;

  hipLaunchKernelGGL(k0_wconv, dim3(2304), dim3(256), 0, stream, weight, wb);

  if (xtpath) hipLaunchKernelGGL(k2a_xT, dim3(1024), dim3(256), 0, stream, x, xT);

  if (xtpath && mfmak1) {
    hipLaunchKernelGGL(k0b_womb, dim3(288), dim3(256), 0, stream, w_om, womb);
    hipLaunchKernelGGL(k1_mfma, dim3(768), dim3(256), 0, stream, womb, xT, ompart);
    hipLaunchKernelGGL(k1b_ppm, dim3(576), dim3(256), 0, stream, ompart, b_om, pypxmk);
  } else {
    hipLaunchKernelGGL(k1_offconv, dim3(4 * 64 * 7), dim3(256), 0, stream, x, w_om, b_om, pypxmk);
  }

  if (xtpath) {
    hipLaunchKernelGGL(k2_cols, dim3(2048), dim3(256), 0, stream, xT, pypxmk, cols);
  } else {
    hipLaunchKernelGGL(k2_fb, dim3(4 * 64 * 16), dim3(256), 0, stream, x, pypxmk, cols);
  }

  if (splitk) {
    hipLaunchKernelGGL(k3_gemm, dim3(768), dim3(256), 0, stream, wb, cols, bias, part, 24, 0);
    hipLaunchKernelGGL(k4_reduce, dim3(4096), dim3(256), 0, stream, part, bias, out);
  } else {
    hipLaunchKernelGGL(k3_gemm, dim3(256), dim3(256), 0, stream, wb, cols, bias, out, 72, 1);
  }
}